// Round 2
// 73.037 us; speedup vs baseline: 1.0235x; 1.0235x over previous
//
#include <hip/hip_runtime.h>

#define BLOCK 512
#define VPT   4        // events per thread
#define ZS    8064     // z0 points staged in LDS (63 KB; leaves room for reduce arrays)

typedef float fx4 __attribute__((ext_vector_type(4)));   // native vector: OK for nontemporal builtins

// Kernel 1: stage z0[0..ZS) into LDS; stream [E,3] data with non-temporal
// float4 loads (keeps L1/L2 for z0; un-staged z0 tail ~15 KB stays L1-hot);
// gathers hit LDS ~81% of the time. Per-block reduce -> float2 partial.
__global__ __launch_bounds__(BLOCK) void nd_partial_kernel(
    const float* __restrict__ data,   // [E,3] row-major: i, j, t
    const float* __restrict__ beta,   // [1]
    const float* __restrict__ z0,     // [N,2]
    float* __restrict__ partials,     // [nblk*2]
    int E)
{
    __shared__ __align__(16) float2 zs[ZS];
    __shared__ float lds1[BLOCK / 64];
    __shared__ float lds2[BLOCK / 64];

    const float2* __restrict__ z2 = (const float2*)z0;

    // cooperative stage: ZS points = ZS/2 float4s
    {
        const float4* __restrict__ z4 = (const float4*)z0;
        float4* zs4 = (float4*)zs;
        for (int k = threadIdx.x; k < ZS / 2; k += BLOCK) zs4[k] = z4[k];
    }
    __syncthreads();

    const float b = beta[0];
    const fx4* __restrict__ d4 = (const fx4*)data;

    float s_log = 0.0f;
    float s_exp = 0.0f;

    int t  = blockIdx.x * BLOCK + threadIdx.x;
    int e0 = t * VPT;

    if (e0 + VPT <= E) {
        // floats 12t..12t+11 = [i0,j0,t0, i1,j1,t1, i2,j2,t2, i3,j3,t3]
        fx4 va = __builtin_nontemporal_load(&d4[3 * t + 0]);
        fx4 vb = __builtin_nontemporal_load(&d4[3 * t + 1]);
        fx4 vc = __builtin_nontemporal_load(&d4[3 * t + 2]);
        int i0 = (int)va.x, j0 = (int)va.y;
        int i1 = (int)va.w, j1 = (int)vb.x;
        int i2 = (int)vb.z, j2 = (int)vb.w;
        int i3 = (int)vc.y, j3 = (int)vc.z;

        float2 pi0 = (i0 < ZS) ? zs[i0] : z2[i0];
        float2 pj0 = (j0 < ZS) ? zs[j0] : z2[j0];
        float2 pi1 = (i1 < ZS) ? zs[i1] : z2[i1];
        float2 pj1 = (j1 < ZS) ? zs[j1] : z2[j1];
        float2 pi2 = (i2 < ZS) ? zs[i2] : z2[i2];
        float2 pj2 = (j2 < ZS) ? zs[j2] : z2[j2];
        float2 pi3 = (i3 < ZS) ? zs[i3] : z2[i3];
        float2 pj3 = (j3 < ZS) ? zs[j3] : z2[j3];

        float dx0 = pi0.x - pj0.x, dy0 = pi0.y - pj0.y;
        float dx1 = pi1.x - pj1.x, dy1 = pi1.y - pj1.y;
        float dx2 = pi2.x - pj2.x, dy2 = pi2.y - pj2.y;
        float dx3 = pi3.x - pj3.x, dy3 = pi3.y - pj3.y;

        float l0 = b - (dx0 * dx0 + dy0 * dy0);
        float l1 = b - (dx1 * dx1 + dy1 * dy1);
        float l2 = b - (dx2 * dx2 + dy2 * dy2);
        float l3 = b - (dx3 * dx3 + dy3 * dy3);

        s_log = (l0 + l1) + (l2 + l3);
        s_exp = (__expf(l0) + __expf(l1)) + (__expf(l2) + __expf(l3));
    } else {
        for (int e = e0; e < E; ++e) {
            int i = (int)data[3 * e + 0];
            int j = (int)data[3 * e + 1];
            float2 pi = (i < ZS) ? zs[i] : z2[i];
            float2 pj = (j < ZS) ? zs[j] : z2[j];
            float dx = pi.x - pj.x, dy = pi.y - pj.y;
            float li = b - (dx * dx + dy * dy);
            s_log += li;
            s_exp += __expf(li);
        }
    }

    // wave (64-lane) butterfly reduce
    for (int off = 32; off > 0; off >>= 1) {
        s_log += __shfl_down(s_log, off, 64);
        s_exp += __shfl_down(s_exp, off, 64);
    }

    int lane = threadIdx.x & 63;
    int wave = threadIdx.x >> 6;
    if (lane == 0) { lds1[wave] = s_log; lds2[wave] = s_exp; }
    __syncthreads();
    if (threadIdx.x == 0) {
        float t1 = 0.0f, t2 = 0.0f;
        #pragma unroll
        for (int w = 0; w < BLOCK / 64; ++w) { t1 += lds1[w]; t2 += lds2[w]; }
        partials[2 * blockIdx.x + 0] = t1;
        partials[2 * blockIdx.x + 1] = t2;
    }
}

// Kernel 2: single block reduces the nblk partials; out = non_event - event.
__global__ __launch_bounds__(256) void nd_final_kernel(
    const float* __restrict__ partials,
    float* __restrict__ out,
    int nblk)
{
    float s1 = 0.0f, s2 = 0.0f;
    for (int idx = threadIdx.x; idx < nblk; idx += 256) {
        s1 += partials[2 * idx + 0];
        s2 += partials[2 * idx + 1];
    }
    for (int off = 32; off > 0; off >>= 1) {
        s1 += __shfl_down(s1, off, 64);
        s2 += __shfl_down(s2, off, 64);
    }
    __shared__ float lds1[4];
    __shared__ float lds2[4];
    int lane = threadIdx.x & 63;
    int wave = threadIdx.x >> 6;
    if (lane == 0) { lds1[wave] = s1; lds2[wave] = s2; }
    __syncthreads();
    if (threadIdx.x == 0) {
        float t1 = 0.0f, t2 = 0.0f;
        #pragma unroll
        for (int w = 0; w < 4; ++w) { t1 += lds1[w]; t2 += lds2[w]; }
        // log_likelihood = event - non_event; return -log_likelihood
        out[0] = t2 - t1;
    }
}

extern "C" void kernel_launch(void* const* d_in, const int* in_sizes, int n_in,
                              void* d_out, int out_size, void* d_ws, size_t ws_size,
                              hipStream_t stream) {
    // setup_inputs order: data, t0, tn, beta, z0
    const float* data = (const float*)d_in[0];
    const float* beta = (const float*)d_in[3];
    const float* z0   = (const float*)d_in[4];
    float* out        = (float*)d_out;
    float* partials   = (float*)d_ws;

    int E = in_sizes[0] / 3;
    int threads = (E + VPT - 1) / VPT;
    int nblk = (threads + BLOCK - 1) / BLOCK;   // 489 for E=1M

    nd_partial_kernel<<<nblk, BLOCK, 0, stream>>>(data, beta, z0, partials, E);
    nd_final_kernel<<<1, 256, 0, stream>>>(partials, out, nblk);
}